// Round 4
// baseline (633.404 us; speedup 1.0000x reference)
//
#include <hip/hip_runtime.h>
#include <hip/hip_bf16.h>

#define N_NODES 100000
#define N_EDGES 1600000
#define N_ROIS  400
#define HID     128
#define N_GRAPHS 512
#define NOUT    2
#define NBUCK   391      // ceil(N_NODES/256), bucket = node >> 8
#define BCAP    8192     // per-bucket edge capacity (mean 4092, 64 sigma margin)
#define ECH     4096     // edges per bucket block
#define NPW     16       // nodes per gather wave
#define NBLK_BUCKET 391  // ceil(N_EDGES/ECH)
#define NBLK_PREP   208  // 13*8*64*8 / 256
#define NBLK_GEMM   782  // ceil(N_NODES/128)
#define SLAB ((size_t)N_NODES * 16)   // shorts per hp column-slice slab

typedef __attribute__((ext_vector_type(8))) short short8;
typedef __attribute__((ext_vector_type(4))) float f32x4;

static __device__ __forceinline__ unsigned short f2bf(float f) {
  unsigned u = __float_as_uint(f);
  u += 0x7fffu + ((u >> 16) & 1u);   // RNE
  return (unsigned short)(u >> 16);
}
static __device__ __forceinline__ float bf2f(unsigned short h) {
  return __uint_as_float(((unsigned)h) << 16);
}

static __device__ __forceinline__ void gload_lds16(const unsigned short* g, short* l) {
  __builtin_amdgcn_global_load_lds(
      (const __attribute__((address_space(1))) void*)g,
      (__attribute__((address_space(3))) void*)l, 16, 0, 0);
}

// ==== L1 fused: blocks [0,391) bucket-append, [391,599) Wf fragment pack ====
__global__ __launch_bounds__(256) void prep_bucket_k(
    const int* __restrict__ row, const int* __restrict__ col,
    int* __restrict__ bcnt, unsigned int* __restrict__ pairs,
    const float* __restrict__ W, unsigned short* __restrict__ Wf) {
  __shared__ int hist[NBUCK];
  __shared__ int base[NBUCK];
  int t = threadIdx.x;
  if (blockIdx.x >= NBLK_BUCKET) {
    int idx = (blockIdx.x - NBLK_BUCKET) * 256 + t;
    if (idx < 13 * 8 * 64 * 8) {
      int u    = idx & 7;
      int lane = (idx >> 3) & 63;
      int nt   = (idx >> 9) & 7;
      int kk5  = idx >> 12;
      int n = nt * 16 + (lane & 15);
      int k = kk5 * 32 + (lane >> 4) * 8 + u;
      Wf[idx] = (k < N_ROIS) ? f2bf(W[k * HID + n]) : (unsigned short)0;
    }
    return;
  }
  for (int b = t; b < NBUCK; b += 256) hist[b] = 0;
  __syncthreads();
  int e0 = blockIdx.x * ECH;
  unsigned int pk[16];
  int bk[16], rk[16];
#pragma unroll
  for (int i = 0; i < 16; ++i) {
    int e = e0 + t + i * 256;
    if (e < N_EDGES) {
      int r = row[e], c = col[e];
      bk[i] = c >> 8;
      pk[i] = ((unsigned)r << 8) | (unsigned)(c & 255);
      rk[i] = atomicAdd(&hist[bk[i]], 1);   // LDS atomic: local rank
    } else bk[i] = -1;
  }
  __syncthreads();
  for (int b = t; b < NBUCK; b += 256)
    base[b] = (hist[b] > 0) ? atomicAdd(&bcnt[b], hist[b]) : 0;
  __syncthreads();
#pragma unroll
  for (int i = 0; i < 16; ++i)
    if (bk[i] >= 0) {
      int p = base[bk[i]] + rk[i];
      if (p < BCAP) pairs[(size_t)bk[i] * BCAP + p] = pk[i];
    }
}

// ==== L2 fused: blocks [0,391) per-bucket CSR build, [391,1173) GEMM ====
// GEMM writes hp in column-sliced layout: hp2[slice=nt][node][16] bf16,
// slab = 3.2 MB -> one slab fits a single XCD's 4 MB L2 (gather relies on it).
__global__ __launch_bounds__(512, 4) void csr_gemm_k(
    const unsigned int* __restrict__ pairs, const int* __restrict__ bcnt,
    int* __restrict__ csr_row, int* __restrict__ offs, int* __restrict__ cnt,
    float* __restrict__ dinv,
    const float* __restrict__ x, const unsigned short* __restrict__ Wf,
    unsigned short* __restrict__ hp2) {
  __shared__ __align__(16) union {
    struct { unsigned int ep[BCAP]; int h[256]; int sc[256]; int cur[256]; } c; // 35.8 KB
    short Bs[28672];                                                            // 57.3 KB
  } u;
  int t = threadIdx.x;

  if (blockIdx.x < NBUCK) {
    // ---- CSR branch: per-node work on t<256, uniform barriers ----
    bool act = t < 256;
    int b = blockIdx.x;
    int m = min(bcnt[b], BCAP);
    size_t base = (size_t)b * BCAP;
    for (int j = t; j < m; j += 512) u.c.ep[j] = pairs[base + j];
    if (act) u.c.h[t] = 0;
    __syncthreads();
    for (int j = t; j < m; j += 512) atomicAdd(&u.c.h[u.c.ep[j] & 255u], 1);
    __syncthreads();
    int myc = act ? u.c.h[t] : 0;
    int mycp = (myc + 3) & ~3;          // pad slot to multiple of 4
    if (act) u.c.sc[t] = mycp;
    __syncthreads();
    for (int off = 1; off < 256; off <<= 1) {
      int v = (act && t >= off) ? u.c.sc[t - off] : 0;
      __syncthreads();
      if (act) u.c.sc[t] += v;
      __syncthreads();
    }
    if (act) {
      int loff = u.c.sc[t] - mycp;      // padded exclusive scan
      u.c.cur[t] = loff;
      int node = b * 256 + t;
      if (node < N_NODES) {
        cnt[node] = myc;
        offs[node] = (int)base + loff;
        dinv[node] = rsqrtf((float)(myc + 1));
      }
    }
    __syncthreads();
    for (int j = t; j < m; j += 512) {
      unsigned int e = u.c.ep[j];
      int pos = atomicAdd(&u.c.cur[e & 255u], 1);   // LDS atomic
      if (pos < BCAP) csr_row[base + pos] = (int)(e >> 8);
    }
    return;
  }

  // ---- GEMM branch: hp2 = bf16(x @ W), no dinv scaling (applied in gather) ----
  int lane = t & 63, wv = t >> 6;
  int mrow = lane & 15, kg = lane >> 4;
  int row0 = (blockIdx.x - NBUCK) * 128;
  int arow = row0 + wv * 16 + mrow;
  bool rowok = arow < N_NODES;
  const float* xp = x + (size_t)arow * N_ROIS;

  f32x4 acc[8];
#pragma unroll
  for (int i = 0; i < 8; ++i) acc[i] = (f32x4){0.f, 0.f, 0.f, 0.f};

  // stage phase A: K-steps 0..6
#pragma unroll
  for (int c = 0; c < 7; ++c) {
    int ch = wv * 7 + c;
    gload_lds16(Wf + (size_t)ch * 512 + lane * 8, &u.Bs[ch * 512]);
  }
  asm volatile("s_waitcnt vmcnt(0)" ::: "memory");
  __syncthreads();

#pragma unroll
  for (int kf = 0; kf < 7; ++kf) {
    int k0 = kf * 32 + kg * 8;
    short8 a8;
    if (rowok && k0 + 8 <= N_ROIS) {
      float4 f0 = *(const float4*)(xp + k0);
      float4 f1 = *(const float4*)(xp + k0 + 4);
      a8[0] = (short)f2bf(f0.x); a8[1] = (short)f2bf(f0.y);
      a8[2] = (short)f2bf(f0.z); a8[3] = (short)f2bf(f0.w);
      a8[4] = (short)f2bf(f1.x); a8[5] = (short)f2bf(f1.y);
      a8[6] = (short)f2bf(f1.z); a8[7] = (short)f2bf(f1.w);
    } else {
#pragma unroll
      for (int v = 0; v < 8; ++v) {
        int k = k0 + v;
        float f = (rowok && k < N_ROIS) ? xp[k] : 0.f;
        a8[v] = (short)f2bf(f);
      }
    }
#pragma unroll
    for (int nt = 0; nt < 8; ++nt) {
      short8 bf = *(const short8*)&u.Bs[(kf * 8 + nt) * 512 + lane * 8];
      acc[nt] = __builtin_amdgcn_mfma_f32_16x16x32_bf16(a8, bf, acc[nt], 0, 0, 0);
    }
  }
  __syncthreads();

  // stage phase B: K-steps 7..12
#pragma unroll
  for (int c = 0; c < 6; ++c) {
    int ch = wv * 6 + c;
    gload_lds16(Wf + (size_t)(56 + ch) * 512 + lane * 8, &u.Bs[ch * 512]);
  }
  asm volatile("s_waitcnt vmcnt(0)" ::: "memory");
  __syncthreads();

#pragma unroll
  for (int kf = 0; kf < 6; ++kf) {
    int k0 = (kf + 7) * 32 + kg * 8;
    short8 a8;
    if (rowok && k0 + 8 <= N_ROIS) {
      float4 f0 = *(const float4*)(xp + k0);
      float4 f1 = *(const float4*)(xp + k0 + 4);
      a8[0] = (short)f2bf(f0.x); a8[1] = (short)f2bf(f0.y);
      a8[2] = (short)f2bf(f0.z); a8[3] = (short)f2bf(f0.w);
      a8[4] = (short)f2bf(f1.x); a8[5] = (short)f2bf(f1.y);
      a8[6] = (short)f2bf(f1.z); a8[7] = (short)f2bf(f1.w);
    } else {
#pragma unroll
      for (int v = 0; v < 8; ++v) {
        int k = k0 + v;
        float f = (rowok && k < N_ROIS) ? xp[k] : 0.f;
        a8[v] = (short)f2bf(f);
      }
    }
#pragma unroll
    for (int nt = 0; nt < 8; ++nt) {
      short8 bf = *(const short8*)&u.Bs[(kf * 8 + nt) * 512 + lane * 8];
      acc[nt] = __builtin_amdgcn_mfma_f32_16x16x32_bf16(a8, bf, acc[nt], 0, 0, 0);
    }
  }

  // epilogue: sliced store — slice index IS nt (col = nt*16 + mrow, mrow<16)
#pragma unroll
  for (int r = 0; r < 4; ++r) {
    int grow = row0 + wv * 16 + kg * 4 + r;
    if (grow < N_NODES) {
#pragma unroll
      for (int nt = 0; nt < 8; ++nt)
        hp2[(size_t)nt * SLAB + (size_t)grow * 16 + mrow] = f2bf(acc[nt][r]);
    }
  }
}

static __device__ __forceinline__ void acc8s(float* a, uint4 u, float d) {
  a[0] = fmaf(d, bf2f((unsigned short)(u.x)), a[0]);
  a[1] = fmaf(d, bf2f((unsigned short)(u.x >> 16)), a[1]);
  a[2] = fmaf(d, bf2f((unsigned short)(u.y)), a[2]);
  a[3] = fmaf(d, bf2f((unsigned short)(u.y >> 16)), a[3]);
  a[4] = fmaf(d, bf2f((unsigned short)(u.z)), a[4]);
  a[5] = fmaf(d, bf2f((unsigned short)(u.z >> 16)), a[5]);
  a[6] = fmaf(d, bf2f((unsigned short)(u.w)), a[6]);
  a[7] = fmaf(d, bf2f((unsigned short)(u.w >> 16)), a[7]);
}

// ---- XCD-sliced aggregation. slice = blockIdx.x & 7 -> round-robin block->XCD
//      mapping pins each 3.2 MB hp slab into ONE XCD's L2 (misses: 177->26 MB).
//      Wave: 32 edge-slots x 2 col-halves (16 B dwordx4 each, 32 B/row). ----
__global__ __launch_bounds__(256) void gather_k(
    const unsigned short* __restrict__ hp2, const int* __restrict__ csr_row,
    const int* __restrict__ offs, const int* __restrict__ cnt,
    const float* __restrict__ dinv, const int* __restrict__ batch,
    const float* __restrict__ bias, unsigned int* __restrict__ pooled_bits) {
  int slice = blockIdx.x & 7;
  int bslot = blockIdx.x >> 3;
  int lane = threadIdx.x & 63;
  int wv = threadIdx.x >> 6;
  int n0 = (bslot * 4 + wv) * NPW;
  if (n0 >= N_NODES) return;
  int nend = min(n0 + NPW, N_NODES);
  int es = lane >> 1;                // edge slot 0..31
  int ch = lane & 1;                 // col half: slice cols ch*8 .. ch*8+7
  const unsigned short* hs = hp2 + (size_t)slice * SLAB;
  float bv[8];
  {
    float4 b0 = *(const float4*)(bias + slice * 16 + ch * 8);
    float4 b1 = *(const float4*)(bias + slice * 16 + ch * 8 + 4);
    bv[0] = b0.x; bv[1] = b0.y; bv[2] = b0.z; bv[3] = b0.w;
    bv[4] = b1.x; bv[5] = b1.y; bv[6] = b1.z; bv[7] = b1.w;
  }
  float rm[8];
#pragma unroll
  for (int k = 0; k < 8; ++k) rm[k] = 0.f;   // relu >= 0 -> 0 is identity
  int cur_g = batch[n0];

  for (int i = n0; i < nend; ++i) {
    int start = offs[i];
    int m = cnt[i];
    float di = dinv[i];
    float a[8];
#pragma unroll
    for (int k = 0; k < 8; ++k) a[k] = 0.f;
    if (es == 0) {                       // self loop, weight dinv[i]
      uint4 u = *(const uint4*)(hs + (size_t)i * 16 + ch * 8);
      acc8s(a, u, di);
    }
    for (int j = 0; j < m; j += 32) {    // 32 edges per step, 1 step typical
      int idx = j + es;
      if (idx < m) {
        int s = csr_row[start + idx];    // pair-shared 4B, 128B/wave coalesced
        float dv = dinv[s];
        uint4 u = *(const uint4*)(hs + (size_t)s * 16 + ch * 8);
        acc8s(a, u, dv);
      }
    }
    // butterfly over the 32 edge-slots (stride-2 lanes share ch)
#pragma unroll
    for (int k = 0; k < 8; ++k) {
      a[k] += __shfl_xor(a[k], 2);
      a[k] += __shfl_xor(a[k], 4);
      a[k] += __shfl_xor(a[k], 8);
      a[k] += __shfl_xor(a[k], 16);
      a[k] += __shfl_xor(a[k], 32);
    }
    int gb = batch[i];
    if (gb != cur_g) {                   // wave-uniform branch
      if (lane < 2) {
#pragma unroll
        for (int k = 0; k < 8; ++k)
          atomicMax(&pooled_bits[cur_g * HID + slice * 16 + ch * 8 + k],
                    __float_as_uint(rm[k]));
      }
#pragma unroll
      for (int k = 0; k < 8; ++k) rm[k] = 0.f;
      cur_g = gb;
    }
#pragma unroll
    for (int k = 0; k < 8; ++k)
      rm[k] = fmaxf(rm[k], fmaxf(fmaf(di, a[k], bv[k]), 0.f));
  }
  if (lane < 2) {
#pragma unroll
    for (int k = 0; k < 8; ++k)
      atomicMax(&pooled_bits[cur_g * HID + slice * 16 + ch * 8 + k],
                __float_as_uint(rm[k]));
  }
}

// ---- logits = pooled @ lin_W + lin_b ----
__global__ void logits_k(const float* __restrict__ pooled, const float* __restrict__ lin_W,
                         const float* __restrict__ lin_b, float* __restrict__ out) {
  int t = blockIdx.x * blockDim.x + threadIdx.x;
  if (t < N_GRAPHS * NOUT) {
    int g = t >> 1, o = t & 1;
    float s = lin_b[o];
    const float* pg = pooled + g * HID;
#pragma unroll 8
    for (int k = 0; k < HID; ++k) s = fmaf(pg[k], lin_W[k * NOUT + o], s);
    out[t] = s;
  }
}

extern "C" void kernel_launch(void* const* d_in, const int* in_sizes, int n_in,
                              void* d_out, int out_size, void* d_ws, size_t ws_size,
                              hipStream_t stream) {
  (void)in_sizes; (void)n_in; (void)ws_size;
  const float* x     = (const float*)d_in[0];
  const int*   ei    = (const int*)d_in[1];
  const int*   row   = ei;             // sources
  const int*   col   = ei + N_EDGES;   // targets
  const int*   batch = (const int*)d_in[2];
  const float* W     = (const float*)d_in[3];
  const float* b     = (const float*)d_in[4];
  const float* lin_W = (const float*)d_in[5];
  const float* lin_b = (const float*)d_in[6];
  float* out = (float*)d_out;

  // workspace layout, 52.5 MB total (hp2 de-aliased from pairs; sliced layout)
  char* ws = (char*)d_ws;
  int*   bcnt    = (int*)(ws + 0);               //   4,096 B (391 used)
  int*   offs    = (int*)(ws + 4096);            // 400,000 B
  int*   cnt     = (int*)(ws + 404096);          // 400,000 B
  float* dinv    = (float*)(ws + 804096);        // 400,000 B
  unsigned short* Wf = (unsigned short*)(ws + 1204096);   // 106,496 B (frag order)
  int*   csr_row = (int*)(ws + 1310720);         // 391*8192*4 = 12,812,288 B
  unsigned int* pairs = (unsigned int*)(ws + 14123008);   // 12,812,288 B
  unsigned short* hp2 = (unsigned short*)(ws + 26935296); // 25,600,000 B, 8 slabs

  hipMemsetAsync(bcnt, 0, NBUCK * sizeof(int), stream);
  hipMemsetAsync(d_out, 0, (size_t)out_size * sizeof(float), stream);

  // L1: bucket-append (391 blocks) || Wf fragment pack (208 blocks)
  prep_bucket_k<<<NBLK_BUCKET + NBLK_PREP, 256, 0, stream>>>(row, col, bcnt, pairs, W, Wf);
  // L2: CSR build (391 blocks) || GEMM (782 blocks) on one grid
  csr_gemm_k<<<NBUCK + NBLK_GEMM, 512, 0, stream>>>(
      pairs, bcnt, csr_row, offs, cnt, dinv, x, Wf, hp2);
  // L3: XCD-sliced gather: 8 slices x 1563 blocks, slice = blockIdx.x & 7
  {
    int waves_per_slice = (N_NODES + NPW - 1) / NPW;        // 6250
    int blocks_per_slice = (waves_per_slice + 3) / 4;       // 1563
    gather_k<<<8 * blocks_per_slice, 256, 0, stream>>>(
        hp2, csr_row, offs, cnt, dinv, batch, b,
        (unsigned int*)(out + N_GRAPHS * NOUT));
  }
  logits_k<<<(N_GRAPHS * NOUT + 255) / 256, 256, 0, stream>>>(
      out + N_GRAPHS * NOUT, lin_W, lin_b, out);
}

// Round 5
// 381.747 us; speedup vs baseline: 1.6592x; 1.6592x over previous
//
#include <hip/hip_runtime.h>
#include <hip/hip_bf16.h>

#define N_NODES 100000
#define N_EDGES 1600000
#define N_ROIS  400
#define HID     128
#define N_GRAPHS 512
#define NOUT    2
#define NBUCK   391      // ceil(N_NODES/256), bucket = node >> 8
#define BCAP    8192     // per-bucket edge capacity (mean 4092, 64 sigma margin)
#define ECH     4096     // edges per bucket block
#define NPW     16       // nodes per gather wave
#define NBLK_BUCKET 391  // ceil(N_EDGES/ECH)
#define NBLK_PREP   208  // 13*8*64*8 / 256
#define NBLK_GEMM   782  // ceil(N_NODES/128)

typedef __attribute__((ext_vector_type(8))) short short8;
typedef __attribute__((ext_vector_type(4))) float f32x4;

static __device__ __forceinline__ unsigned short f2bf(float f) {
  unsigned u = __float_as_uint(f);
  u += 0x7fffu + ((u >> 16) & 1u);   // RNE
  return (unsigned short)(u >> 16);
}
static __device__ __forceinline__ float bf2f(unsigned short h) {
  return __uint_as_float(((unsigned)h) << 16);
}

static __device__ __forceinline__ void gload_lds16(const unsigned short* g, short* l) {
  __builtin_amdgcn_global_load_lds(
      (const __attribute__((address_space(1))) void*)g,
      (__attribute__((address_space(3))) void*)l, 16, 0, 0);
}

// ==== L1 fused: blocks [0,391) bucket-append (LDS counting sort -> coalesced
//      pairs writes), [391,599) Wf fragment pack ====
__global__ __launch_bounds__(256) void prep_bucket_k(
    const int* __restrict__ row, const int* __restrict__ col,
    int* __restrict__ bcnt, unsigned int* __restrict__ pairs,
    const float* __restrict__ W, unsigned short* __restrict__ Wf) {
  __shared__ int hist[NBUCK];
  __shared__ int lbase[NBUCK];            // block-local exclusive prefix
  __shared__ int adj[NBUCK];              // global in-bucket base (atomic old)
  __shared__ unsigned int spk[ECH];       // packed edges sorted by bucket
  __shared__ unsigned short sbk[ECH];     // bucket id per sorted slot
  __shared__ int sc[256];
  int t = threadIdx.x;
  if (blockIdx.x >= NBLK_BUCKET) {
    int idx = (blockIdx.x - NBLK_BUCKET) * 256 + t;
    if (idx < 13 * 8 * 64 * 8) {
      int u    = idx & 7;
      int lane = (idx >> 3) & 63;
      int nt   = (idx >> 9) & 7;
      int kk5  = idx >> 12;
      int n = nt * 16 + (lane & 15);
      int k = kk5 * 32 + (lane >> 4) * 8 + u;
      Wf[idx] = (k < N_ROIS) ? f2bf(W[k * HID + n]) : (unsigned short)0;
    }
    return;
  }
  for (int b = t; b < NBUCK; b += 256) hist[b] = 0;
  __syncthreads();
  int e0 = blockIdx.x * ECH;
  int mtot = min(ECH, N_EDGES - e0);
  unsigned int pk[16];
  int bk[16], rk[16];
#pragma unroll
  for (int i = 0; i < 16; ++i) {
    int e = e0 + t + i * 256;
    if (e < N_EDGES) {
      int r = row[e], c = col[e];
      bk[i] = c >> 8;
      pk[i] = ((unsigned)r << 8) | (unsigned)(c & 255);
      rk[i] = atomicAdd(&hist[bk[i]], 1);   // LDS atomic: local rank
    } else bk[i] = -1;
  }
  __syncthreads();
  // exclusive scan of hist[0..391) -> lbase, in two 256-wide passes
  int v0 = hist[t];
  sc[t] = v0;
  __syncthreads();
  for (int off = 1; off < 256; off <<= 1) {
    int v = (t >= off) ? sc[t - off] : 0;
    __syncthreads();
    sc[t] += v;
    __syncthreads();
  }
  lbase[t] = sc[t] - v0;
  int tot0 = sc[255];
  __syncthreads();
  int v1 = (t < NBUCK - 256) ? hist[256 + t] : 0;
  sc[t] = v1;
  __syncthreads();
  for (int off = 1; off < 256; off <<= 1) {
    int v = (t >= off) ? sc[t - off] : 0;
    __syncthreads();
    sc[t] += v;
    __syncthreads();
  }
  if (t < NBUCK - 256) lbase[256 + t] = tot0 + sc[t] - v1;
  __syncthreads();
  // scatter into LDS in bucket-sorted order
#pragma unroll
  for (int i = 0; i < 16; ++i)
    if (bk[i] >= 0) {
      int pos = lbase[bk[i]] + rk[i];
      spk[pos] = pk[i];
      sbk[pos] = (unsigned short)bk[i];
    }
  // reserve global ranges
  for (int b = t; b < NBUCK; b += 256)
    adj[b] = (hist[b] > 0) ? atomicAdd(&bcnt[b], hist[b]) : 0;
  __syncthreads();
  // linear write: consecutive j -> consecutive dst within each bucket run
  for (int j = t; j < mtot; j += 256) {
    int b = sbk[j];
    int p = adj[b] + (j - lbase[b]);
    if (p < BCAP) pairs[(size_t)b * BCAP + p] = spk[j];
  }
}

// ==== L2 fused: blocks [0,391) per-bucket CSR build (LDS sort -> fully linear
//      csr_row writes), [391,1173) GEMM ====
__global__ __launch_bounds__(512, 4) void csr_gemm_k(
    const unsigned int* __restrict__ pairs, const int* __restrict__ bcnt,
    int* __restrict__ csr_row, int* __restrict__ offs, int* __restrict__ cnt,
    float* __restrict__ dinv,
    const float* __restrict__ x, const unsigned short* __restrict__ Wf,
    unsigned short* __restrict__ hp) {
  __shared__ __align__(16) union {
    struct {
      unsigned int ep[BCAP];   // 32 KB
      int ssr[BCAP];           // 32 KB node-sorted sources
      int h[256]; int sc2[256]; int cur[256];
    } c;                       // 68.6 KB
    short Bs[28672];           // 57.3 KB
  } u;
  int t = threadIdx.x;

  if (blockIdx.x < NBUCK) {
    // ---- CSR branch: per-node work on t<256, uniform barriers ----
    bool act = t < 256;
    int b = blockIdx.x;
    int m = min(bcnt[b], BCAP);
    size_t base = (size_t)b * BCAP;
    for (int j = t; j < m; j += 512) u.c.ep[j] = pairs[base + j];
    if (act) u.c.h[t] = 0;
    __syncthreads();
    for (int j = t; j < m; j += 512) atomicAdd(&u.c.h[u.c.ep[j] & 255u], 1);
    __syncthreads();
    int myc = act ? u.c.h[t] : 0;
    int mycp = (myc + 3) & ~3;          // pad slot to multiple of 4
    if (act) u.c.sc2[t] = mycp;
    __syncthreads();
    for (int off = 1; off < 256; off <<= 1) {
      int v = (act && t >= off) ? u.c.sc2[t - off] : 0;
      __syncthreads();
      if (act) u.c.sc2[t] += v;
      __syncthreads();
    }
    if (act) {
      int loff = u.c.sc2[t] - mycp;     // padded exclusive scan
      u.c.cur[t] = loff;
      int node = b * 256 + t;
      if (node < N_NODES) {
        cnt[node] = myc;
        offs[node] = (int)base + loff;
        dinv[node] = rsqrtf((float)(myc + 1));
      }
    }
    __syncthreads();
    // scatter into LDS (node-sorted); padding gaps hold garbage, never read
    for (int j = t; j < m; j += 512) {
      unsigned int e = u.c.ep[j];
      int pos = atomicAdd(&u.c.cur[e & 255u], 1);   // LDS atomic
      if (pos < BCAP) u.c.ssr[pos] = (int)(e >> 8);
    }
    __syncthreads();
    int tpad = u.c.sc2[255];            // padded total for this bucket
    if (tpad > BCAP) tpad = BCAP;
    for (int j = t; j < tpad; j += 512) csr_row[base + j] = u.c.ssr[j];
    return;
  }

  // ---- GEMM branch: hp = bf16(x @ W), no dinv scaling (applied in gather) ----
  int lane = t & 63, wv = t >> 6;
  int mrow = lane & 15, kg = lane >> 4;
  int row0 = (blockIdx.x - NBUCK) * 128;
  int arow = row0 + wv * 16 + mrow;
  bool rowok = arow < N_NODES;
  const float* xp = x + (size_t)arow * N_ROIS;

  f32x4 acc[8];
#pragma unroll
  for (int i = 0; i < 8; ++i) acc[i] = (f32x4){0.f, 0.f, 0.f, 0.f};

  // stage phase A: K-steps 0..6
#pragma unroll
  for (int c = 0; c < 7; ++c) {
    int ch = wv * 7 + c;
    gload_lds16(Wf + (size_t)ch * 512 + lane * 8, &u.Bs[ch * 512]);
  }
  asm volatile("s_waitcnt vmcnt(0)" ::: "memory");
  __syncthreads();

#pragma unroll
  for (int kf = 0; kf < 7; ++kf) {
    int k0 = kf * 32 + kg * 8;
    short8 a8;
    if (rowok && k0 + 8 <= N_ROIS) {
      float4 f0 = *(const float4*)(xp + k0);
      float4 f1 = *(const float4*)(xp + k0 + 4);
      a8[0] = (short)f2bf(f0.x); a8[1] = (short)f2bf(f0.y);
      a8[2] = (short)f2bf(f0.z); a8[3] = (short)f2bf(f0.w);
      a8[4] = (short)f2bf(f1.x); a8[5] = (short)f2bf(f1.y);
      a8[6] = (short)f2bf(f1.z); a8[7] = (short)f2bf(f1.w);
    } else {
#pragma unroll
      for (int v = 0; v < 8; ++v) {
        int k = k0 + v;
        float f = (rowok && k < N_ROIS) ? xp[k] : 0.f;
        a8[v] = (short)f2bf(f);
      }
    }
#pragma unroll
    for (int nt = 0; nt < 8; ++nt) {
      short8 bf = *(const short8*)&u.Bs[(kf * 8 + nt) * 512 + lane * 8];
      acc[nt] = __builtin_amdgcn_mfma_f32_16x16x32_bf16(a8, bf, acc[nt], 0, 0, 0);
    }
  }
  __syncthreads();

  // stage phase B: K-steps 7..12
#pragma unroll
  for (int c = 0; c < 6; ++c) {
    int ch = wv * 6 + c;
    gload_lds16(Wf + (size_t)(56 + ch) * 512 + lane * 8, &u.Bs[ch * 512]);
  }
  asm volatile("s_waitcnt vmcnt(0)" ::: "memory");
  __syncthreads();

#pragma unroll
  for (int kf = 0; kf < 6; ++kf) {
    int k0 = (kf + 7) * 32 + kg * 8;
    short8 a8;
    if (rowok && k0 + 8 <= N_ROIS) {
      float4 f0 = *(const float4*)(xp + k0);
      float4 f1 = *(const float4*)(xp + k0 + 4);
      a8[0] = (short)f2bf(f0.x); a8[1] = (short)f2bf(f0.y);
      a8[2] = (short)f2bf(f0.z); a8[3] = (short)f2bf(f0.w);
      a8[4] = (short)f2bf(f1.x); a8[5] = (short)f2bf(f1.y);
      a8[6] = (short)f2bf(f1.z); a8[7] = (short)f2bf(f1.w);
    } else {
#pragma unroll
      for (int v = 0; v < 8; ++v) {
        int k = k0 + v;
        float f = (rowok && k < N_ROIS) ? xp[k] : 0.f;
        a8[v] = (short)f2bf(f);
      }
    }
#pragma unroll
    for (int nt = 0; nt < 8; ++nt) {
      short8 bf = *(const short8*)&u.Bs[(kf * 8 + nt) * 512 + lane * 8];
      acc[nt] = __builtin_amdgcn_mfma_f32_16x16x32_bf16(a8, bf, acc[nt], 0, 0, 0);
    }
  }

#pragma unroll
  for (int r = 0; r < 4; ++r) {
    int grow = row0 + wv * 16 + kg * 4 + r;
    if (grow < N_NODES) {
      unsigned short* op = hp + (size_t)grow * HID + mrow;
#pragma unroll
      for (int nt = 0; nt < 8; ++nt) op[nt * 16] = f2bf(acc[nt][r]);
    }
  }
}

static __device__ __forceinline__ void acc8s(float* a, uint4 u, float d) {
  a[0] = fmaf(d, bf2f((unsigned short)(u.x)), a[0]);
  a[1] = fmaf(d, bf2f((unsigned short)(u.x >> 16)), a[1]);
  a[2] = fmaf(d, bf2f((unsigned short)(u.y)), a[2]);
  a[3] = fmaf(d, bf2f((unsigned short)(u.y >> 16)), a[3]);
  a[4] = fmaf(d, bf2f((unsigned short)(u.z)), a[4]);
  a[5] = fmaf(d, bf2f((unsigned short)(u.z >> 16)), a[5]);
  a[6] = fmaf(d, bf2f((unsigned short)(u.w)), a[6]);
  a[7] = fmaf(d, bf2f((unsigned short)(u.w >> 16)), a[7]);
}

// ---- aggregation (round-3 structure, measured 94 us = random-fabric floor) ----
__global__ __launch_bounds__(256) void gather_k(
    const unsigned short* __restrict__ hp, const int* __restrict__ csr_row,
    const int* __restrict__ offs, const int* __restrict__ cnt,
    const float* __restrict__ dinv, const int* __restrict__ batch,
    const float* __restrict__ bias, unsigned int* __restrict__ pooled_bits) {
  int wave = (blockIdx.x * blockDim.x + threadIdx.x) >> 6;
  int lane = threadIdx.x & 63;
  int g  = lane >> 4;        // edge-slot group 0..3
  int cg = lane & 15;        // column group: cols cg*8 .. cg*8+7
  int n0 = wave * NPW;
  if (n0 >= N_NODES) return;
  int nend = min(n0 + NPW, N_NODES);
  float bv[8];
  {
    float4 b0 = *(const float4*)(bias + cg * 8);
    float4 b1 = *(const float4*)(bias + cg * 8 + 4);
    bv[0] = b0.x; bv[1] = b0.y; bv[2] = b0.z; bv[3] = b0.w;
    bv[4] = b1.x; bv[5] = b1.y; bv[6] = b1.z; bv[7] = b1.w;
  }
  float rm[8];
#pragma unroll
  for (int k = 0; k < 8; ++k) rm[k] = 0.f;   // relu >= 0 -> 0 is identity
  int cur_g = batch[n0];

  for (int i = n0; i < nend; ++i) {
    int start = offs[i];
    int m = cnt[i];
    float di = dinv[i];
    float a[8];
#pragma unroll
    for (int k = 0; k < 8; ++k) a[k] = 0.f;
    if (g == 0) {                         // self loop: weight dinv[i]
      uint4 u = *(const uint4*)(hp + (size_t)i * HID + cg * 8);
      acc8s(a, u, di);
    }
    for (int j = 0; j < m; j += 4) {
      int4 q = *(const int4*)(csr_row + start + j);  // wave-uniform, aligned
      int s = (g == 0) ? q.x : (g == 1) ? q.y : (g == 2) ? q.z : q.w;
      if (j + g < m) {
        float dv = dinv[s];
        uint4 u = *(const uint4*)(hp + (size_t)s * HID + cg * 8);
        acc8s(a, u, dv);
      }
    }
    // butterfly: sum the 4 edge-slot groups
#pragma unroll
    for (int k = 0; k < 8; ++k) {
      a[k] += __shfl_xor(a[k], 16);
      a[k] += __shfl_xor(a[k], 32);
    }
    int gb = batch[i];
    if (gb != cur_g) {                    // wave-uniform branch
      if (lane < 16) {
#pragma unroll
        for (int k = 0; k < 8; ++k)
          atomicMax(&pooled_bits[cur_g * HID + cg * 8 + k], __float_as_uint(rm[k]));
      }
#pragma unroll
      for (int k = 0; k < 8; ++k) rm[k] = 0.f;
      cur_g = gb;
    }
#pragma unroll
    for (int k = 0; k < 8; ++k)
      rm[k] = fmaxf(rm[k], fmaxf(fmaf(di, a[k], bv[k]), 0.f));
  }
  if (lane < 16) {
#pragma unroll
    for (int k = 0; k < 8; ++k)
      atomicMax(&pooled_bits[cur_g * HID + cg * 8 + k], __float_as_uint(rm[k]));
  }
}

// ---- logits = pooled @ lin_W + lin_b ----
__global__ void logits_k(const float* __restrict__ pooled, const float* __restrict__ lin_W,
                         const float* __restrict__ lin_b, float* __restrict__ out) {
  int t = blockIdx.x * blockDim.x + threadIdx.x;
  if (t < N_GRAPHS * NOUT) {
    int g = t >> 1, o = t & 1;
    float s = lin_b[o];
    const float* pg = pooled + g * HID;
#pragma unroll 8
    for (int k = 0; k < HID; ++k) s = fmaf(pg[k], lin_W[k * NOUT + o], s);
    out[t] = s;
  }
}

extern "C" void kernel_launch(void* const* d_in, const int* in_sizes, int n_in,
                              void* d_out, int out_size, void* d_ws, size_t ws_size,
                              hipStream_t stream) {
  (void)in_sizes; (void)n_in; (void)ws_size;
  const float* x     = (const float*)d_in[0];
  const int*   ei    = (const int*)d_in[1];
  const int*   row   = ei;             // sources
  const int*   col   = ei + N_EDGES;   // targets
  const int*   batch = (const int*)d_in[2];
  const float* W     = (const float*)d_in[3];
  const float* b     = (const float*)d_in[4];
  const float* lin_W = (const float*)d_in[5];
  const float* lin_b = (const float*)d_in[6];
  float* out = (float*)d_out;

  // workspace layout, 52.5 MB total (hp de-aliased from pairs for L2 fusion)
  char* ws = (char*)d_ws;
  int*   bcnt    = (int*)(ws + 0);               //   4,096 B (391 used)
  int*   offs    = (int*)(ws + 4096);            // 400,000 B
  int*   cnt     = (int*)(ws + 404096);          // 400,000 B
  float* dinv    = (float*)(ws + 804096);        // 400,000 B
  unsigned short* Wf = (unsigned short*)(ws + 1204096);   // 106,496 B (frag order)
  int*   csr_row = (int*)(ws + 1310720);         // 391*8192*4 = 12,812,288 B
  unsigned int* pairs = (unsigned int*)(ws + 14123008);   // 12,812,288 B
  unsigned short* hp  = (unsigned short*)(ws + 26935296); // 25,600,000 B

  hipMemsetAsync(bcnt, 0, NBUCK * sizeof(int), stream);
  hipMemsetAsync(d_out, 0, (size_t)out_size * sizeof(float), stream);

  // L1: bucket-append (391 blocks, LDS-sorted coalesced writes) || Wf pack (208)
  prep_bucket_k<<<NBLK_BUCKET + NBLK_PREP, 256, 0, stream>>>(row, col, bcnt, pairs, W, Wf);
  // L2: CSR build (391 blocks, linear csr_row writes) || GEMM (782) on one grid
  csr_gemm_k<<<NBUCK + NBLK_GEMM, 512, 0, stream>>>(
      pairs, bcnt, csr_row, offs, cnt, dinv, x, Wf, hp);
  // L3: gather (random-fabric floor ~94 us)
  {
    int waves = (N_NODES + NPW - 1) / NPW;             // 6250
    int blocks = (waves * 64 + 255) / 256;             // 1563
    gather_k<<<blocks, 256, 0, stream>>>(
        hp, csr_row, offs, cnt, dinv, batch, b,
        (unsigned int*)(out + N_GRAPHS * NOUT));
  }
  logits_k<<<(N_GRAPHS * NOUT + 255) / 256, 256, 0, stream>>>(
      out + N_GRAPHS * NOUT, lin_W, lin_b, out);
}